// Round 11
// baseline (441.912 us; speedup 1.0000x reference)
//
#include <hip/hip_runtime.h>

#define N_NODES 8192
#define IN_F    256
#define OUT_F   128
#define ALPHA_S 0.2f

typedef __attribute__((ext_vector_type(8))) short  short8;
typedef __attribute__((ext_vector_type(4))) short  short4v;
typedef __attribute__((ext_vector_type(4))) float  floatx4;
typedef __attribute__((ext_vector_type(4))) int    intx4;
typedef __attribute__((ext_vector_type(4))) float  fx4;

static __device__ __forceinline__ float bf2f(short s) {
    union { unsigned int i; float f; } u;
    u.i = ((unsigned int)(unsigned short)s) << 16;
    return u.f;
}
static __device__ __forceinline__ short f2bf(float f) {
    union { float f; unsigned int i; } u; u.f = f;
    unsigned int r = u.i + 0x7FFFu + ((u.i >> 16) & 1u);  // RNE
    return (short)(r >> 16);
}

// ---------------------------------------------------------------------------
// k_wh: Wh = h @ W via bf16 MFMA -> fragment-major WhB[jblk][ft][lane][8].
//       src/dst fp32-exact via q1=W@a1, q2=W@a2 folded into W staging.
// 256 blocks x 512 threads. (validated R10; unchanged)
// ---------------------------------------------------------------------------
__global__ __launch_bounds__(512) void k_wh(
    const float* __restrict__ h, const float* __restrict__ W,
    const float* __restrict__ a,
    short* __restrict__ WhB, float* __restrict__ src, float* __restrict__ dst)
{
    __shared__ short Wt[OUT_F][IN_F + 8];
    __shared__ short htile[32][IN_F + 8];
    __shared__ float q1s[IN_F], q2s[IN_F];
    __shared__ short wh_t[OUT_F][40];

    const int t      = threadIdx.x;
    const int lane   = t & 63;
    const int wave   = t >> 6;
    const int r_base = blockIdx.x * 32;

#pragma unroll
    for (int rep = 0; rep < 4; ++rep) {
        const int idx = rep * 8192 + t * 16;
        const int k   = idx >> 7;
        const int f   = idx & 127;
        fx4 w0 = *(const fx4*)(W + idx);
        fx4 w1 = *(const fx4*)(W + idx + 4);
        fx4 w2 = *(const fx4*)(W + idx + 8);
        fx4 w3 = *(const fx4*)(W + idx + 12);
        fx4 a10 = *(const fx4*)(a + f);
        fx4 a11 = *(const fx4*)(a + f + 4);
        fx4 a12 = *(const fx4*)(a + f + 8);
        fx4 a13 = *(const fx4*)(a + f + 12);
        fx4 a20 = *(const fx4*)(a + OUT_F + f);
        fx4 a21 = *(const fx4*)(a + OUT_F + f + 4);
        fx4 a22 = *(const fx4*)(a + OUT_F + f + 8);
        fx4 a23 = *(const fx4*)(a + OUT_F + f + 12);
        float p1 = 0.f, p2 = 0.f;
#pragma unroll
        for (int e = 0; e < 4; ++e) {
            p1 = fmaf(w0[e], a10[e], p1); p2 = fmaf(w0[e], a20[e], p2);
            p1 = fmaf(w1[e], a11[e], p1); p2 = fmaf(w1[e], a21[e], p2);
            p1 = fmaf(w2[e], a12[e], p1); p2 = fmaf(w2[e], a22[e], p2);
            p1 = fmaf(w3[e], a13[e], p1); p2 = fmaf(w3[e], a23[e], p2);
        }
#pragma unroll
        for (int e = 0; e < 4; ++e) {
            Wt[f + e][k]      = f2bf(w0[e]);
            Wt[f + 4 + e][k]  = f2bf(w1[e]);
            Wt[f + 8 + e][k]  = f2bf(w2[e]);
            Wt[f + 12 + e][k] = f2bf(w3[e]);
        }
#pragma unroll
        for (int m = 1; m < 8; m <<= 1) {
            p1 += __shfl_xor(p1, m, 64);
            p2 += __shfl_xor(p2, m, 64);
        }
        if ((t & 7) == 0) { q1s[k] = p1; q2s[k] = p2; }
    }

    const int r0   = t >> 4;
    const int fgrp = t & 15;
    const int k0   = fgrp * 16;
    fx4 h0, h1, h2, h3;
    {
        const float* hp = h + (size_t)(r_base + r0) * IN_F + k0;
        h0 = *(const fx4*)hp; h1 = *(const fx4*)(hp + 4);
        h2 = *(const fx4*)(hp + 8); h3 = *(const fx4*)(hp + 12);
        short8 b0, b1;
#pragma unroll
        for (int e = 0; e < 4; ++e) {
            b0[e]     = f2bf(h0[e]); b0[4 + e] = f2bf(h1[e]);
            b1[e]     = f2bf(h2[e]); b1[4 + e] = f2bf(h3[e]);
        }
        *(short8*)&htile[r0][k0]     = b0;
        *(short8*)&htile[r0][k0 + 8] = b1;
    }
    __syncthreads();

    {
        float sp = 0.f, dp = 0.f;
#pragma unroll
        for (int e = 0; e < 4; ++e) {
            sp = fmaf(h0[e], q1s[k0 + e], sp);      dp = fmaf(h0[e], q2s[k0 + e], dp);
            sp = fmaf(h1[e], q1s[k0 + 4 + e], sp);  dp = fmaf(h1[e], q2s[k0 + 4 + e], dp);
            sp = fmaf(h2[e], q1s[k0 + 8 + e], sp);  dp = fmaf(h2[e], q2s[k0 + 8 + e], dp);
            sp = fmaf(h3[e], q1s[k0 + 12 + e], sp); dp = fmaf(h3[e], q2s[k0 + 12 + e], dp);
        }
#pragma unroll
        for (int m = 1; m < 16; m <<= 1) {
            sp += __shfl_xor(sp, m, 64);
            dp += __shfl_xor(dp, m, 64);
        }
        if (fgrp == 0) { src[r_base + r0] = sp; dst[r_base + r0] = dp; }
    }

    const int ln15 = lane & 15;
    const int q    = lane >> 4;
    const int f0   = wave * 16;
    floatx4 c0 = {0.f, 0.f, 0.f, 0.f};
    floatx4 c1 = {0.f, 0.f, 0.f, 0.f};
#pragma unroll
    for (int s = 0; s < 8; ++s) {
        short8 bf  = *(const short8*)&Wt[f0 + ln15][s * 32 + q * 8];
        short8 a0f = *(const short8*)&htile[ln15][s * 32 + q * 8];
        short8 a1f = *(const short8*)&htile[16 + ln15][s * 32 + q * 8];
        c0 = __builtin_amdgcn_mfma_f32_16x16x32_bf16(a0f, bf, c0, 0, 0, 0);
        c1 = __builtin_amdgcn_mfma_f32_16x16x32_bf16(a1f, bf, c1, 0, 0, 0);
    }
    {
        short4v p0, p1;
#pragma unroll
        for (int r = 0; r < 4; ++r) { p0[r] = f2bf(c0[r]); p1[r] = f2bf(c1[r]); }
        *(short4v*)&wh_t[f0 + ln15][q * 4]      = p0;
        *(short4v*)&wh_t[f0 + ln15][16 + q * 4] = p1;
    }
    __syncthreads();
    {
        const int ft2 = t >> 6;
        const int l2  = t & 63;
        const int n2  = l2 & 15;
        const int q2  = l2 >> 4;
        short8 v = *(const short8*)&wh_t[ft2 * 16 + n2][q2 * 8];
        *(short8*)(WhB + (((size_t)blockIdx.x * 8 + ft2) * 64 + l2) * 8) = v;
    }
}

// ---------------------------------------------------------------------------
// k_weights: PURE STREAM. thread -> 16 contiguous j of one row.
// Read adj (64 B/thread, coalesced), compute exp weight, write bf16 P
// (32 B/thread, coalesced). Row-sum partials (of bf16-rounded values ==
// exactly the numerator terms) block-reduced, plain store (no atomics).
// grid 16384 (= 8192 rows x 2 half-rows) x 256 threads.
// ---------------------------------------------------------------------------
__global__ __launch_bounds__(256) void k_weights(
    const int*   __restrict__ adj,
    const float* __restrict__ src,
    const float* __restrict__ dstv,
    short* __restrict__ P,            // [N][N] bf16
    float* __restrict__ denom_part)   // [2][N] fp32
{
    __shared__ float wsum[4];
    const int bi  = blockIdx.x;
    const int row = bi >> 1;
    const int c0  = (bi & 1) * 4096;
    const int t   = threadIdx.x;
    const int col = c0 + t * 16;

    const float srow = src[row];
    const int*   ap = adj + (size_t)row * N_NODES + col;
    const float* dp = dstv + col;

    intx4 m[4]; fx4 d[4];
#pragma unroll
    for (int v = 0; v < 4; ++v) {
        m[v] = *(const intx4*)(ap + v * 4);
        d[v] = *(const fx4*)(dp + v * 4);
    }

    short8 w0, w1;
    float lsum = 0.f;
#pragma unroll
    for (int v = 0; v < 4; ++v) {
#pragma unroll
        for (int e = 0; e < 4; ++e) {
            float x = srow + d[v][e];
            float l = fmaxf(x, ALPHA_S * x);
            short b = (m[v][e] > 0) ? f2bf(__expf(l)) : (short)0;
            lsum += bf2f(b);
            if (v < 2) w0[v * 4 + e] = b;
            else       w1[(v - 2) * 4 + e] = b;
        }
    }
    short* pp = P + (size_t)row * N_NODES + col;
    *(short8*)pp       = w0;
    *(short8*)(pp + 8) = w1;

    // block-reduce lsum (256 threads)
#pragma unroll
    for (int s = 1; s < 64; s <<= 1) lsum += __shfl_xor(lsum, s, 64);
    if ((t & 63) == 0) wsum[t >> 6] = lsum;
    __syncthreads();
    if (t == 0)
        denom_part[(size_t)(bi & 1) * N_NODES + row] =
            wsum[0] + wsum[1] + wsum[2] + wsum[3];
}

// ---------------------------------------------------------------------------
// k_pv: numer = P @ Wh. Skinny GEMM, K-split 8.
// grid 512 (= 64 rowgroups x 8 k-chunks) x 512 threads (8 waves).
// Wave w owns f-tile ft=w (no duplicated B traffic), all 128 rows (acc[8]).
// A staged via LDS (coalesced, 2 barriers/iter, m97 pattern), BK=128.
// B from fragment-major WhB (1 coalesced short8 per frag, L2-hot).
// ---------------------------------------------------------------------------
#define KSPLIT 8
#define KCH  (N_NODES / KSPLIT)   // 1024
#define PBK  128
#define PSTR (PBK + 8)            // 136 shorts
#define PNIT (KCH / PBK)          // 8

__global__ __launch_bounds__(512) void k_pv(
    const short* __restrict__ P,      // [N][N] bf16
    const short* __restrict__ WhB,    // [N/32][8][64][8] bf16
    float* __restrict__ numer_part)   // [8][N][OUT_F] fp32
{
    __shared__ short atile[128 * PSTR];   // 34.8 KB

    const int t    = threadIdx.x;
    const int lane = t & 63;
    const int wave = t >> 6;              // 0..7 = ft
    const int rg   = blockIdx.x >> 3;     // 0..63
    const int kc   = blockIdx.x & 7;      // 0..7
    const int r0   = rg * 128;
    const int kb   = kc * KCH;
    const int jb0  = kb >> 5;             // base jblk

    const int ln15 = lane & 15;
    const int q    = lane >> 4;

    // staging mapping: thread -> (row t>>2, 32 k at (t&3)*32)
    const int srow2 = t >> 2;
    const int sc    = (t & 3) * 32;
    const short* pgl = P + (size_t)(r0 + srow2) * N_NODES + kb + sc;
    short* lw = &atile[srow2 * PSTR + sc];

    floatx4 acc[8];
#pragma unroll
    for (int rt = 0; rt < 8; ++rt) acc[rt] = (floatx4){0.f, 0.f, 0.f, 0.f};

    for (int it = 0; it < PNIT; ++it) {
        __syncthreads();   // previous compute done before overwrite
        {
            const short* pg = pgl + it * PBK;
#pragma unroll
            for (int u = 0; u < 4; ++u)
                *(short8*)(lw + u * 8) = *(const short8*)(pg + u * 8);
        }
        __syncthreads();
        const short* bbase = WhB + (((size_t)(jb0 + it * 4) * 8 + wave) * 64 + lane) * 8;
#pragma unroll
        for (int kf = 0; kf < 4; ++kf) {
            short8 Bf = *(const short8*)(bbase + (size_t)kf * 8 * 64 * 8);
#pragma unroll
            for (int rt = 0; rt < 8; ++rt) {
                short8 Af = *(const short8*)&atile[(rt * 16 + ln15) * PSTR + kf * 32 + q * 8];
                acc[rt] = __builtin_amdgcn_mfma_f32_16x16x32_bf16(Af, Bf, acc[rt], 0, 0, 0);
            }
        }
    }

    // epilogue: plain stores. C-layout: row = q*4+r, col f = wave*16 + ln15.
    float* np = numer_part + ((size_t)kc * N_NODES + r0) * OUT_F + wave * 16 + ln15;
#pragma unroll
    for (int rt = 0; rt < 8; ++rt)
#pragma unroll
        for (int r = 0; r < 4; ++r)
            np[(size_t)(rt * 16 + q * 4 + r) * OUT_F] = acc[rt][r];
}

// ---------------------------------------------------------------------------
// k_final: out = ELU( (sum_kc numer) / (sum_half denom) ).
// ---------------------------------------------------------------------------
__global__ void k_final(const float* __restrict__ numer_part,
                        const float* __restrict__ denom_part,
                        float* __restrict__ out) {
    const int idx = blockIdx.x * 256 + threadIdx.x;   // grid 4096
    const int row = idx >> 7;
    float v = 0.f;
#pragma unroll
    for (int kc = 0; kc < KSPLIT; ++kc)
        v += numer_part[(size_t)kc * N_NODES * OUT_F + idx];
    float dn = denom_part[row] + denom_part[N_NODES + row];
    v = (dn != 0.f) ? (v / dn) : 0.f;
    v = v > 0.f ? v : (__expf(v) - 1.f);
    out[idx] = v;
}

// ---------------------------------------------------------------------------
extern "C" void kernel_launch(void* const* d_in, const int* in_sizes, int n_in,
                              void* d_out, int out_size, void* d_ws, size_t ws_size,
                              hipStream_t stream) {
    const float* h   = (const float*)d_in[0];   // fp32 [8192][256]
    const int*   adj = (const int*)d_in[1];     // int32 [8192][8192]
    const float* W   = (const float*)d_in[2];   // fp32 [256][128]
    const float* a   = (const float*)d_in[3];   // fp32 [256]
    float* out = (float*)d_out;                 // fp32 [8192][128]

    char*  ws         = (char*)d_ws;
    float* denom_part = (float*)ws;                             // 64 KB [2][N]
    short* WhB        = (short*)(ws + (256 << 10));             // 2 MB
    float* src        = (float*)(ws + (256 << 10) + (2 << 20)); // 32 KB
    float* dst        = src + N_NODES;                          // 32 KB
    float* numer_part = (float*)(ws + (4 << 20));               // 32 MB
    short* P          = (short*)(ws + (64ull << 20));           // 128 MB

    k_wh      <<<256, 512, 0, stream>>>(h, W, a, WhB, src, dst);
    k_weights <<<16384, 256, 0, stream>>>(adj, src, dst, P, denom_part);
    k_pv      <<<512, 512, 0, stream>>>(P, WhB, numer_part);
    k_final   <<<4096, 256, 0, stream>>>(numer_part, denom_part, out);
}